// Round 5
// baseline (888.903 us; speedup 1.0000x reference)
//
#include <hip/hip_runtime.h>
#include <hip/hip_bf16.h>

// B=16, N=1024, R=10, De=64, Dr=32, H=64, cat_in=960
// out[b,m,h] = relu( bias[h] + sum_r sum_n adj[b,r,m,n] * Yt[br,h,n] )
// Yt[br,h,n] = sum_d x[b,n,d]*W[h, r*96+d] + c[br,h]
// c[br,h]    = sum_d rel[br,d]*W[h, r*96+64+d]

typedef __bf16 bf16x8 __attribute__((ext_vector_type(8)));
typedef float  f32x4  __attribute__((ext_vector_type(4)));

// ---------------- prep kernel: c (fused) + Yt[br,h,n] (bf16, linear) ----------------
__global__ __launch_bounds__(256)
void rgcn_prep(const float* __restrict__ x, const float* __restrict__ rel,
               const float* __restrict__ W, __bf16* __restrict__ yt) {
    const int r = blockIdx.y, b = blockIdx.z;
    const int br = b * 10 + r;

    __shared__ float csh[64];
    if (threadIdx.x < 64) {
        const int h = threadIdx.x;
        const float* rp = rel + (size_t)br * 32;
        const float* wp = W + (size_t)h * 960 + r * 96 + 64;
        float a = 0.f;
#pragma unroll
        for (int d = 0; d < 32; ++d) a += rp[d] * wp[d];
        csh[h] = a;
    }
    __syncthreads();

    const int n = blockIdx.x * 256 + threadIdx.x;   // 0..1023
    float xr[64];
    const float* xp = x + ((size_t)b * 1024 + n) * 64;
#pragma unroll
    for (int j = 0; j < 16; ++j) {
        const float4 v = *(const float4*)(xp + j * 4);
        xr[j * 4 + 0] = v.x; xr[j * 4 + 1] = v.y;
        xr[j * 4 + 2] = v.z; xr[j * 4 + 3] = v.w;
    }

    const float* wbase = W + r * 96;                 // W[h*960 + r*96 + d]
    __bf16* yb = yt + ((size_t)br << 16) + n;        // Yt[br][h][n], linear
    for (int h = 0; h < 64; ++h) {                   // h,d wave-uniform -> W scalar loads
        float acc = csh[h];
        const float* wr = wbase + (size_t)h * 960;
#pragma unroll
        for (int d = 0; d < 64; ++d) acc += xr[d] * wr[d];
        yb[(size_t)h << 10] = (__bf16)acc;
    }
}

// ---------------- main kernel: contiguous adj staging through LDS ----------------
// grid (160/NREL, 8 mtile), 512 thr = 8 waves; wave owns 16m x 64h; block 128 rows.
// Per relation: 8 fills of A[128 m][128 k] (each thread loads a CONTIGUOUS 128B row
// run = 8x dwordx4, cvt->bf16 in reg, ds_write swizzled); Yt staged per quarter
// [64 h][256 k]. LDS 64 KB -> 2 blocks/CU. T14: two A reg-sets, next fill issued
// before current consumed (counted vmcnt, HBM never drains); Y regs issued one
// fill ahead of use so their wait never drains the A queue.
// Swizzle (elem): k ^= (row&7)<<3 -> all LDS ops 2-way (free).
// A-frag: row=lm, k=g*8+j ; B-frag same k-map (k-perm cancels).
// C/D: col=lane&15 (h), row=(lane>>4)*4+reg (m) — validated rounds 1-4.
template<int NREL, bool FUSE>
__global__ __launch_bounds__(512, 4)
void rgcn_main(const float* __restrict__ adj, const __bf16* __restrict__ yt,
               float* __restrict__ partial, const float* __restrict__ bias,
               float* __restrict__ dst) {
    const int bx = blockIdx.x, mtile = blockIdx.y;
    const int tid = threadIdx.x;
    const int w = tid >> 6, lane = tid & 63;
    const int g = lane >> 4, lm = lane & 15;

    __shared__ __bf16 shA[128 * 128];   // 32 KB
    __shared__ __bf16 shY[64 * 256];    // 32 KB

    const int arow = tid >> 2;              // 0..127  A row staged by this thread
    const int aseg = (tid & 3) * 32;        // col base within fill (f32 elems)
    const int yrow = tid >> 3;              // 0..63   Y row staged by this thread
    const int yseg = (tid & 7) * 32;        // col base within quarter (bf16 elems)
    const int fsw  = (lm & 7) << 3;         // fragment-read swizzle

    f32x4 acc[4] = {};

    for (int rr = 0; rr < NREL; ++rr) {
        const int br = bx * NREL + rr;
        const float*  abase = adj + (((size_t)(br * 1024 + mtile * 128 + arow)) << 10) + aseg;
        const __bf16* ybase = yt + ((size_t)br << 16) + ((size_t)yrow << 10) + yseg;

        f32x4 ar[2][8];
        uint4 yr[4];

        // preload: quarter 0 Y + fill 0 A
#pragma unroll
        for (int i = 0; i < 4; ++i) yr[i] = *(const uint4*)(ybase + i * 8);
#pragma unroll
        for (int j = 0; j < 8; ++j)
            ar[0][j] = __builtin_nontemporal_load((const f32x4*)(abase + j * 4));

#pragma unroll 2
        for (int f = 0; f < 8; ++f) {
            const int cs = f & 1;           // static under unroll-2

            // issue next quarter's Y loads (odd f), then next fill's A loads
            if (cs == 1 && f < 7) {
                const __bf16* yq = ybase + ((f + 1) >> 1) * 256;
#pragma unroll
                for (int i = 0; i < 4; ++i) yr[i] = *(const uint4*)(yq + i * 8);
            }
            if (f < 7) {
                const float* af = abase + (f + 1) * 128;
#pragma unroll
                for (int j = 0; j < 8; ++j)
                    ar[cs ^ 1][j] = __builtin_nontemporal_load((const f32x4*)(af + j * 4));
            }

            __syncthreads();                // prior fill's LDS reads complete

            if (cs == 0) {                  // stage Y quarter f>>1
#pragma unroll
                for (int i = 0; i < 4; ++i)
                    *(uint4*)(shY + yrow * 256 + ((yseg + i * 8) ^ ((yrow & 7) << 3))) = yr[i];
            }
            // cvt + stage A fill f
#pragma unroll
            for (int jp = 0; jp < 4; ++jp) {
                const f32x4 u = ar[cs][jp * 2], v = ar[cs][jp * 2 + 1];
                bf16x8 t8;
#pragma unroll
                for (int e = 0; e < 4; ++e) { t8[e] = (__bf16)u[e]; t8[4 + e] = (__bf16)v[e]; }
                *(bf16x8*)(shA + arow * 128 + ((aseg + jp * 8) ^ ((arow & 7) << 3))) = t8;
            }

            __syncthreads();                // staged data visible

            // 4 MFMA k-steps over this fill
#pragma unroll
            for (int s = 0; s < 4; ++s) {
                const int kk = s * 32 + g * 8;
                const bf16x8 av = *(const bf16x8*)(shA + (w * 16 + lm) * 128 + (kk ^ fsw));
#pragma unroll
                for (int hf = 0; hf < 4; ++hf) {
                    const int h = hf * 16 + lm;
                    const bf16x8 bv =
                        *(const bf16x8*)(shY + h * 256 + ((cs * 128 + kk) ^ fsw));
                    acc[hf] = __builtin_amdgcn_mfma_f32_16x16x32_bf16(av, bv, acc[hf], 0, 0, 0);
                }
            }
        }
    }

    // ---- epilogue ----
    if (FUSE) {
        const int b = bx;                   // NREL==10 path
        float* db = dst + (((size_t)b << 10) + mtile * 128 + w * 16) * 64;
#pragma unroll
        for (int hf = 0; hf < 4; ++hf) {
            const float bb = bias[hf * 16 + lm];
#pragma unroll
            for (int reg = 0; reg < 4; ++reg) {
                const int ml = g * 4 + reg;
                db[(size_t)ml * 64 + hf * 16 + lm] = fmaxf(acc[hf][reg] + bb, 0.f);
            }
        }
    } else {
        const int b = bx / 10, r0 = bx % 10;  // NREL==1 path
        float* pb = partial + (((size_t)(r0 * 16 + b)) << 16)
                  + (size_t)(mtile * 128 + w * 16) * 64;
#pragma unroll
        for (int hf = 0; hf < 4; ++hf)
#pragma unroll
            for (int reg = 0; reg < 4; ++reg) {
                const int ml = g * 4 + reg;
                pb[(size_t)ml * 64 + hf * 16 + lm] = acc[hf][reg];
            }
    }
}

// ---------------- epilogue: sum 10 partial slices + bias + relu ----------------
__global__ __launch_bounds__(256)
void rgcn_epi(const float* __restrict__ partial, const float* __restrict__ bias,
              float* __restrict__ dst) {
    const size_t i = (size_t)blockIdx.x * 256 + threadIdx.x;  // f32x4 index, 262144 total
    const size_t off = i * 4;                                  // float idx into [16][1024][64]
    const size_t b = off >> 16;
    const size_t inner = off & 65535;
    f32x4 s = {};
#pragma unroll
    for (int p = 0; p < 10; ++p)
        s += *(const f32x4*)(partial + (((size_t)(p * 16) + b) << 16) + inner);
    const f32x4 bv = *(const f32x4*)(bias + (int)(off & 63));
#pragma unroll
    for (int j = 0; j < 4; ++j) s[j] = fmaxf(s[j] + bv[j], 0.f);
    *(f32x4*)(dst + off) = s;
}

extern "C" void kernel_launch(void* const* d_in, const int* in_sizes, int n_in,
                              void* d_out, int out_size, void* d_ws, size_t ws_size,
                              hipStream_t stream) {
    const float* x   = (const float*)d_in[0];   // [16,1024,64]
    const float* rel = (const float*)d_in[1];   // [16,10,32]
    const float* adj = (const float*)d_in[2];   // [16,10,1024,1024]
    const float* W0  = (const float*)d_in[3];   // [64,960]
    const float* b0  = (const float*)d_in[4];   // [64]
    const float* W1  = (const float*)d_in[5];
    const float* b1  = (const float*)d_in[6];
    float* out = (float*)d_out;                 // [16,1024,64]

    char* ws = (char*)d_ws;
    __bf16* Yt  = (__bf16*)ws;                  // 20,971,520 B (160 x 64 x 1024 bf16)
    float* x2   = (float*)(ws + 20971520);      //  4,194,304 B
    float* part = (float*)(ws + 25165824);      // 41,943,040 B (160 x 65536 f32)
    const size_t need1 = 25165824u + 41943040u;

    for (int layer = 0; layer < 2; ++layer) {
        const float* xin  = layer ? x2 : x;
        const float* W    = layer ? W1 : W0;
        const float* bias = layer ? b1 : b0;
        float* dst        = layer ? out : x2;

        rgcn_prep<<<dim3(4, 10, 16), 256, 0, stream>>>(xin, rel, W, Yt);
        if (ws_size >= need1) {
            rgcn_main<1, false><<<dim3(160, 8), 512, 0, stream>>>(adj, Yt, part, nullptr, nullptr);
            rgcn_epi<<<1024, 256, 0, stream>>>(part, bias, dst);
        } else {
            rgcn_main<10, true><<<dim3(16, 8), 512, 0, stream>>>(adj, Yt, nullptr, bias, dst);
        }
    }
}

// Round 6
// 646.770 us; speedup vs baseline: 1.3744x; 1.3744x over previous
//
#include <hip/hip_runtime.h>
#include <hip/hip_bf16.h>

// B=16, N=1024, R=10, De=64, Dr=32, H=64, cat_in=960
// out[b,m,h] = relu( bias[h] + sum_r sum_n adj[b,r,m,n] * Yt[br,h,n] )
// Yt[br,h,n] = sum_d x[b,n,d]*W[h, r*96+d] + c[br,h]
// c[br,h]    = sum_d rel[br,d]*W[h, r*96+64+d]

typedef __bf16 bf16x8 __attribute__((ext_vector_type(8)));
typedef float  f32x4  __attribute__((ext_vector_type(4)));

// ---------------- prep kernel: c (fused) + Yt[br,h,n] (bf16, linear) ----------------
__global__ __launch_bounds__(256)
void rgcn_prep(const float* __restrict__ x, const float* __restrict__ rel,
               const float* __restrict__ W, __bf16* __restrict__ yt) {
    const int r = blockIdx.y, b = blockIdx.z;
    const int br = b * 10 + r;

    __shared__ float csh[64];
    if (threadIdx.x < 64) {
        const int h = threadIdx.x;
        const float* rp = rel + (size_t)br * 32;
        const float* wp = W + (size_t)h * 960 + r * 96 + 64;
        float a = 0.f;
#pragma unroll
        for (int d = 0; d < 32; ++d) a += rp[d] * wp[d];
        csh[h] = a;
    }
    __syncthreads();

    const int n = blockIdx.x * 256 + threadIdx.x;   // 0..1023
    float xr[64];
    const float* xp = x + ((size_t)b * 1024 + n) * 64;
#pragma unroll
    for (int j = 0; j < 16; ++j) {
        const float4 v = *(const float4*)(xp + j * 4);
        xr[j * 4 + 0] = v.x; xr[j * 4 + 1] = v.y;
        xr[j * 4 + 2] = v.z; xr[j * 4 + 3] = v.w;
    }

    const float* wbase = W + r * 96;                 // W[h*960 + r*96 + d]
    __bf16* yb = yt + ((size_t)br << 16) + n;        // Yt[br][h][n], linear
    for (int h = 0; h < 64; ++h) {                   // h,d wave-uniform -> W scalar loads
        float acc = csh[h];
        const float* wr = wbase + (size_t)h * 960;
#pragma unroll
        for (int d = 0; d < 64; ++d) acc += xr[d] * wr[d];
        yb[(size_t)h << 10] = (__bf16)acc;
    }
}

// ---------------- main kernel: contiguous 64-KB adj batches ----------------
// grid (16 b, 64 mslab), 512 thr = 8 waves, 1 block/CU. Block accumulates ALL 10
// relations for rows [ms*16, ms*16+16) -> writes final out (no partial/epi).
// Per relation: adj batch = 16 adjacent rows x 4 KB = ONE contiguous 64 KB region
// (the DRAM-page-locality fix). T14 split: issue batch r+1 at phase top; convert +
// ds_write after the alpha barrier. Raw s_barrier + sched_barrier(0) fences; the
// compiler emits COUNTED vmcnt for the reg deps (no drain-0 across barriers).
// Y fragments in registers (reloaded per r from XCD-colocated L2: XCD = b%8,
// 2 b per XCD -> 2.5 MB Yt working set < 4 MB L2).
// Waves split k 8-ways (wave w: k in [w*128,(w+1)*128)); LDS tree-reduce at end.
// LDS A tile [16][1024] bf16, 16-B chunks swizzled c ^= (row&7): write & read 2-way.
// Frags (validated r1-r5): A lane=(m=lm, k=g*8+j); B lane=(h=hf*16+lm, same k);
// C/D: h=lm, m=g*4+reg.
__global__ __launch_bounds__(512, 2)
void rgcn_main(const float* __restrict__ adj, const __bf16* __restrict__ yt,
               const float* __restrict__ bias, float* __restrict__ dst) {
    const int b  = blockIdx.x;       // 0..15
    const int ms = blockIdx.y;       // 0..63
    const int tid = threadIdx.x;
    const int w = tid >> 6, lane = tid & 63;
    const int g = lane >> 4, lm = lane & 15;
    const int l31 = lane & 31, lh = lane >> 5;

    __shared__ __attribute__((aligned(16))) char smem[32768];
    float* shR = (float*)smem;       // reduction view [8][1024]

    const int arow = 2 * w + lh;     // row within 16-row slab this thread stages

    f32x4 ar[8];                     // staged adj batch: 128 B/thread
    bf16x8 yf[16];                   // Y frags: [kc][hf]
    f32x4 acc[4] = {};

    const float* aptr = adj + (((size_t)(b * 10) * 1024 + ms * 16 + arow) << 10) + l31 * 8;
    const __bf16* ybase = yt + ((size_t)(b * 10) << 16) + ((size_t)lm << 10) + w * 128 + g * 8;

#define ISSUE_A(rr) { const float* ap = aptr + (size_t)(rr) * 1048576;          \
    _Pragma("unroll") for (int i = 0; i < 4; ++i) {                             \
        ar[2*i]   = __builtin_nontemporal_load((const f32x4*)(ap + i * 256));   \
        ar[2*i+1] = __builtin_nontemporal_load((const f32x4*)(ap + i * 256 + 4)); } }

#define LOAD_Y(rr) { const __bf16* yp = ybase + ((size_t)(rr) << 16);           \
    _Pragma("unroll") for (int kc = 0; kc < 4; ++kc)                            \
    _Pragma("unroll") for (int hf = 0; hf < 4; ++hf)                            \
        yf[kc*4+hf] = *(const bf16x8*)(yp + hf * 16384 + kc * 32); }

#define WRITE_A() { _Pragma("unroll") for (int i = 0; i < 4; ++i) {             \
        bf16x8 t8;                                                              \
        _Pragma("unroll") for (int e = 0; e < 4; ++e) {                         \
            t8[e] = (__bf16)ar[2*i][e]; t8[4+e] = (__bf16)ar[2*i+1][e]; }       \
        *(bf16x8*)(smem + arow * 2048 + (((l31 + 32*i) ^ (arow & 7)) << 4)) = t8; } }

#define COMPUTE() { _Pragma("unroll") for (int kc = 0; kc < 4; ++kc) {          \
        const bf16x8 av = *(const bf16x8*)(smem + lm * 2048 +                   \
                            (((w * 16 + kc * 4 + g) ^ (lm & 7)) << 4));         \
        _Pragma("unroll") for (int hf = 0; hf < 4; ++hf)                        \
            acc[hf] = __builtin_amdgcn_mfma_f32_16x16x32_bf16(av, yf[kc*4+hf], acc[hf], 0, 0, 0); } }

    // prologue: batch 0 + Y 0
    ISSUE_A(0)
    LOAD_Y(0)
    WRITE_A()                                        // auto counted vmcnt on ar
    asm volatile("s_waitcnt lgkmcnt(0)" ::: "memory");
    __builtin_amdgcn_sched_barrier(0);
    __builtin_amdgcn_s_barrier();
    __builtin_amdgcn_sched_barrier(0);

    for (int r = 0; r < 10; ++r) {
        if (r < 9) ISSUE_A(r + 1)                    // HBM batch r+1 in flight
        __builtin_amdgcn_sched_barrier(0);
        COMPUTE()                                    // reads LDS A(r) + yf(r)
        if (r < 9) LOAD_Y(r + 1)                     // L2; after MFMAs (WAR on yf)
        __builtin_amdgcn_sched_barrier(0);
        __builtin_amdgcn_s_barrier();                // alpha: block done reading A(r)
        __builtin_amdgcn_sched_barrier(0);
        if (r < 9) {
            WRITE_A()                                // waits ar (counted), converts, stores
            asm volatile("s_waitcnt lgkmcnt(0)" ::: "memory");
        }
        __builtin_amdgcn_sched_barrier(0);
        __builtin_amdgcn_s_barrier();                // beta: A(r+1) visible
        __builtin_amdgcn_sched_barrier(0);
    }

    // ---- cross-wave k-reduction in LDS (smem reused; all barriers passed) ----
#pragma unroll
    for (int hf = 0; hf < 4; ++hf)
#pragma unroll
        for (int reg = 0; reg < 4; ++reg)
            shR[w * 1024 + (g * 4 + reg) * 64 + hf * 16 + lm] = acc[hf][reg];
    asm volatile("s_waitcnt lgkmcnt(0)" ::: "memory");
    __builtin_amdgcn_sched_barrier(0);
    __builtin_amdgcn_s_barrier();
    __builtin_amdgcn_sched_barrier(0);

    {
        const int e0 = tid * 2;                      // element in [16 m][64 h]
        float s0 = 0.f, s1 = 0.f;
#pragma unroll
        for (int s = 0; s < 8; ++s) {
            s0 += shR[s * 1024 + e0];
            s1 += shR[s * 1024 + e0 + 1];
        }
        const int h0 = e0 & 63;
        s0 = fmaxf(s0 + bias[h0], 0.f);
        s1 = fmaxf(s1 + bias[h0 + 1], 0.f);
        float2 o = {s0, s1};
        *(float2*)(dst + (((size_t)b << 10) + ms * 16) * 64 + e0) = o;
    }
#undef ISSUE_A
#undef LOAD_Y
#undef WRITE_A
#undef COMPUTE
}

extern "C" void kernel_launch(void* const* d_in, const int* in_sizes, int n_in,
                              void* d_out, int out_size, void* d_ws, size_t ws_size,
                              hipStream_t stream) {
    const float* x   = (const float*)d_in[0];   // [16,1024,64]
    const float* rel = (const float*)d_in[1];   // [16,10,32]
    const float* adj = (const float*)d_in[2];   // [16,10,1024,1024]
    const float* W0  = (const float*)d_in[3];   // [64,960]
    const float* b0  = (const float*)d_in[4];   // [64]
    const float* W1  = (const float*)d_in[5];
    const float* b1  = (const float*)d_in[6];
    float* out = (float*)d_out;                 // [16,1024,64]

    char* ws = (char*)d_ws;
    __bf16* Yt = (__bf16*)ws;                   // 20,971,520 B (160 x 64 x 1024 bf16)
    float* x2  = (float*)(ws + 20971520);       //  4,194,304 B (layer-1 activations)

    for (int layer = 0; layer < 2; ++layer) {
        const float* xin  = layer ? x2 : x;
        const float* W    = layer ? W1 : W0;
        const float* bias = layer ? b1 : b0;
        float* dst        = layer ? out : x2;

        rgcn_prep<<<dim3(4, 10, 16), 256, 0, stream>>>(xin, rel, W, Yt);
        rgcn_main<<<dim3(16, 64), 512, 0, stream>>>(adj, Yt, bias, dst);
    }
}